// Round 12
// baseline (369.339 us; speedup 1.0000x reference)
//
#include <hip/hip_runtime.h>
#include <hip/hip_bf16.h>

#define IN_D 128
#define BN_EPS 1e-5f

typedef short bf8 __attribute__((ext_vector_type(8)));   // 8 bf16 = 4 VGPR (guide §3)
typedef float f32x4 __attribute__((ext_vector_type(4)));

__device__ __forceinline__ ushort f2bf(float f) {        // f32 -> bf16 RNE
    unsigned u = __float_as_uint(f);
    unsigned r = u + 0x7fffu + ((u >> 16) & 1u);
    return (ushort)(r >> 16);
}

// ---------------- CSR build ----------------
// edge_index staged int32. csr entry = 4B: {src:16 | bf16(weight):16}.
// 4B entries keep the scatter range (3.2MB) inside one XCD L2 (4MB) -> write coalescing.

__global__ void k_hist(const int* __restrict__ ei, int* __restrict__ deg, int E, int n) {
    int e = blockIdx.x * 256 + threadIdx.x;
    if (e < E) {
        int dst = ei[E + e];
        if (dst >= 0 && dst < n) atomicAdd(&deg[dst], 1);
    }
}

__global__ void k_block_sum(const int* __restrict__ deg, int* __restrict__ bsum, int n) {
    __shared__ int sdata[256];
    int i = blockIdx.x * 256 + threadIdx.x;
    int v = (i < n) ? deg[i] : 0;
    sdata[threadIdx.x] = v;
    __syncthreads();
    for (int s = 128; s > 0; s >>= 1) {
        if (threadIdx.x < s) sdata[threadIdx.x] += sdata[threadIdx.x + s];
        __syncthreads();
    }
    if (threadIdx.x == 0) bsum[blockIdx.x] = sdata[0];
}

__global__ void k_scan_bsum(int* __restrict__ bsum, int nb) {
    __shared__ int s[256];
    int t = threadIdx.x;
    int v = (t < nb) ? bsum[t] : 0;
    s[t] = v;
    __syncthreads();
    for (int off = 1; off < 256; off <<= 1) {
        int u = (t >= off) ? s[t - off] : 0;
        __syncthreads();
        s[t] += u;
        __syncthreads();
    }
    if (t < nb) bsum[t] = s[t] - v;  // exclusive
}

__global__ void k_scan_deg(const int* __restrict__ deg, const int* __restrict__ boff,
                           int* __restrict__ rowptr, int* __restrict__ cursor,
                           float* __restrict__ invcnt, int n) {
    __shared__ int s[256];
    int t = threadIdx.x;
    int i = blockIdx.x * 256 + t;
    int v = (i < n) ? deg[i] : 0;
    s[t] = v;
    __syncthreads();
    for (int off = 1; off < 256; off <<= 1) {
        int u = (t >= off) ? s[t - off] : 0;
        __syncthreads();
        s[t] += u;
        __syncthreads();
    }
    int incl = s[t];
    int excl = incl - v;
    int base = boff[blockIdx.x];
    if (i < n) {
        rowptr[i] = base + excl;
        cursor[i] = base + excl;
        invcnt[i] = 1.0f / (float)(v < 1 ? 1 : v);
        if (i == n - 1) rowptr[n] = base + incl;
    }
}

__global__ void k_fill(const int* __restrict__ ei, const float* __restrict__ ew,
                       int* __restrict__ cursor, unsigned* __restrict__ csr, int E,
                       int n) {
    int e = blockIdx.x * 256 + threadIdx.x;
    if (e < E) {
        int dst = ei[E + e];
        int src = ei[e];
        if (dst < 0 || dst >= n) return;
        if (src < 0) src = 0;
        if (src >= n) src = n - 1;
        int slot = atomicAdd(&cursor[dst], 1);
        csr[slot] = (unsigned)(src & 0xffff) | ((unsigned)f2bf(ew[e]) << 16);
    }
}

// ---------------- x (f32) -> xb (bf16) ----------------
__global__ void k_cvt(const float4* __restrict__ X4, ushort4* __restrict__ Ob, int n4) {
    int i = blockIdx.x * 256 + threadIdx.x;
    if (i < n4) {
        float4 f = X4[i];
        ushort4 o;
        o.x = f2bf(f.x); o.y = f2bf(f.y); o.z = f2bf(f.z); o.w = f2bf(f.w);
        Ob[i] = o;
    }
}

// ---------------- W -> B-fragment-ordered bf16 pack (unchanged) ----------------
__global__ void k_prep(const float* __restrict__ W1l, const float* __restrict__ W1r,
                       const float* __restrict__ W2l, const float* __restrict__ W2r,
                       const float* __restrict__ W3l, const float* __restrict__ W3r,
                       ushort* __restrict__ WB1, ushort* __restrict__ WB2,
                       ushort* __restrict__ WB3) {
    int e = blockIdx.x * 256 + threadIdx.x;  // 0..81919
    const float *Wl, *Wr;
    ushort* dst;
    int idx;
    if (e < 32768)      { Wl = W1l; Wr = W1r; dst = WB1; idx = e; }
    else if (e < 65536) { Wl = W2l; Wr = W2r; dst = WB2; idx = e - 32768; }
    else                { Wl = W3l; Wr = W3r; dst = WB3; idx = e - 65536; }
    int ei = idx & 7, j0 = (idx >> 3) & 15, g = (idx >> 7) & 3, kc = (idx >> 9) & 7,
        jc = idx >> 12;
    int ksrc = (kc & 3) * 32 + g * 8 + ei;
    int jsrc = jc * 16 + j0;
    const float* src = (kc < 4) ? Wl : Wr;
    dst[idx] = f2bf(src[jsrc * 128 + ksrc]);
}

// ---------------- aggregation v2: 2 edges/load-instr, 8 edges in flight ----------
// one wave per node. half = lane>>5 picks edge parity; dl = lane&31 owns 8B (4 dims).
// Per u: csr entry (4B, 2 distinct addrs/wave) -> row gather 8B/lane (256B/edge).
// Final shfl_xor(32) merges the two edge-halves; lanes 0-31 write the 256B row.
__global__ void k_agg(const uint2* __restrict__ X4, const int* __restrict__ rowptr,
                      const unsigned* __restrict__ csr, const float* __restrict__ invcnt,
                      uint2* __restrict__ M4, int n) {
    int wid = (blockIdx.x * blockDim.x + threadIdx.x) >> 6;
    int lane = threadIdx.x & 63;
    if (wid >= n) return;
    int beg = __builtin_amdgcn_readfirstlane(rowptr[wid]);
    int end = __builtin_amdgcn_readfirstlane(rowptr[wid + 1]);
    int half = lane >> 5;
    int dl = lane & 31;
    float a0 = 0.f, a1 = 0.f, a2 = 0.f, a3 = 0.f;
    for (int k = beg; k < end; k += 8) {
#pragma unroll
        for (int u = 0; u < 4; ++u) {
            int kk = k + u * 2 + half;
            unsigned e = (kk < end) ? csr[kk] : 0u;   // e=0 -> w=+0, src=0 (no-op)
            float w = __uint_as_float(e & 0xffff0000u);
            int src = e & 0xffff;
            uint2 v = X4[(size_t)src * 32 + dl];
            a0 += w * __uint_as_float(v.x << 16);
            a1 += w * __uint_as_float(v.x & 0xffff0000u);
            a2 += w * __uint_as_float(v.y << 16);
            a3 += w * __uint_as_float(v.y & 0xffff0000u);
        }
    }
    a0 += __shfl_xor(a0, 32);
    a1 += __shfl_xor(a1, 32);
    a2 += __shfl_xor(a2, 32);
    a3 += __shfl_xor(a3, 32);
    if (half == 0) {
        float ic = invcnt[wid];
        uint2 o;
        o.x = (unsigned)f2bf(a0 * ic) | ((unsigned)f2bf(a1 * ic) << 16);
        o.y = (unsigned)f2bf(a2 * ic) | ((unsigned)f2bf(a3 * ic) << 16);
        M4[(size_t)wid * 32 + dl] = o;
    }
}

// ---------------- GEMM v5: bf16 MFMA (unchanged from round 9/11) ----------------
template <int DO, int BN_FLAG>
__global__ __launch_bounds__(256) void k_gemm5(
    const ushort* __restrict__ Mb, const ushort* __restrict__ Xb,
    const ushort* __restrict__ WB, const float* __restrict__ bias,
    const float* __restrict__ bng, const float* __restrict__ bnb,
    const float* __restrict__ bnm, const float* __restrict__ bnv,
    void* __restrict__ OutP, int n) {
    constexpr int CF = DO / 64;
    __shared__ ushort sAb[32 * 256];  // 16 KB: [node][k] bf16, XOR-swizzled
    __shared__ float ssrow[32];

    int t = threadIdx.x;
    int wv = t >> 6;
    int lane = t & 63;
    int rowl = lane & 15;
    int g = lane >> 4;
    int node0 = blockIdx.x * 32;

    // ---- stage A = [M | X] tile (32 x 256 bf16), swizzle byte ^= (node&7)<<4 ----
    {
        const uint4* Ms = (const uint4*)(Mb + (size_t)node0 * 128);
        const uint4* Xs = (const uint4*)(Xb + (size_t)node0 * 128);
        uint4 z = make_uint4(0, 0, 0, 0);
#pragma unroll
        for (int it = 0; it < 4; ++it) {
            int idx = it * 256 + t;      // 1024 16B-units
            int nd = idx >> 5;           // node 0..31
            int u = idx & 31;            // 16B unit within 512B row
            bool ok = (node0 + nd) < n;
            uint4 vv = ok ? (u < 16 ? Ms[nd * 16 + u] : Xs[nd * 16 + (u - 16)]) : z;
            int byte = nd * 512 + ((u * 16) ^ ((nd & 7) << 4));
            *(uint4*)((char*)sAb + byte) = vv;
        }
        if (BN_FLAG == 0 && t < 32) ssrow[t] = 0.f;
    }
    __syncthreads();

    // ---- MFMA main loop: K = 256 = 8 kc-steps of 32 ----
    f32x4 acc[2][CF];
#pragma unroll
    for (int nf = 0; nf < 2; ++nf)
#pragma unroll
        for (int cf = 0; cf < CF; ++cf) acc[nf][cf] = (f32x4)0.f;

#pragma unroll
    for (int kc = 0; kc < 8; ++kc) {
        bf8 a[2];
#pragma unroll
        for (int nf = 0; nf < 2; ++nf) {
            int nl = nf * 16 + rowl;  // A-frag: row = lane&15, k = g*8+e
            int byte = nl * 512 + (((kc * 64) + g * 16) ^ ((nl & 7) << 4));
            a[nf] = *(const bf8*)((const char*)sAb + byte);
        }
#pragma unroll
        for (int cf = 0; cf < CF; ++cf) {
            int jc = wv * CF + cf;
            bf8 b = *(const bf8*)(WB + (((jc * 8 + kc) * 4 + g) * 128 + rowl * 8));
#pragma unroll
            for (int nf = 0; nf < 2; ++nf)
                acc[nf][cf] =
                    __builtin_amdgcn_mfma_f32_16x16x32_bf16(a[nf], b, acc[nf][cf], 0, 0, 0);
        }
    }

    // ---- epilogue ----
    if constexpr (BN_FLAG) {
        __syncthreads();               // done reading sAb; reuse as H tile
        ushort* sH = sAb;              // [32][DO] bf16
#pragma unroll
        for (int cf = 0; cf < CF; ++cf) {
            int j = (wv * CF + cf) * 16 + rowl;
            float bj = bias[j];
            float gm = bng[j], bb = bnb[j], mm = bnm[j];
            float iv = rsqrtf(bnv[j] + BN_EPS);
#pragma unroll
            for (int nf = 0; nf < 2; ++nf) {
#pragma unroll
                for (int r = 0; r < 4; ++r) {
                    int nrow = nf * 16 + g * 4 + r;  // C layout: row=(lane>>4)*4+r
                    float h = acc[nf][cf][r] + bj;
                    h = (h - mm) * (gm * iv) + bb;
                    h = h >= 0.f ? h : 0.1f * h;
                    sH[nrow * DO + j] = f2bf(h);
                }
            }
        }
        __syncthreads();
        ushort* Hout = (ushort*)OutP;
        constexpr int UPR = DO / 8;    // 16B-units per row
#pragma unroll
        for (int it = 0; it < (32 * UPR) / 256; ++it) {
            int u = it * 256 + t;
            int nd = u / UPR, c = u % UPR;
            if (node0 + nd < n)
                *(uint4*)(Hout + (size_t)(node0 + nd) * DO + c * 8) =
                    *(uint4*)&sH[nd * DO + c * 8];
        }
    } else {
        // DO==64, CF==1: bias + row L2-normalize, f32 out
        float* Outf = (float*)OutP;
        int j = wv * 16 + rowl;
        float bj = bias[j];
        float h[2][4];
#pragma unroll
        for (int nf = 0; nf < 2; ++nf)
#pragma unroll
            for (int r = 0; r < 4; ++r) {
                h[nf][r] = acc[nf][0][r] + bj;
                float s = h[nf][r] * h[nf][r];
                s += __shfl_xor(s, 1);   // reduce over 16 cols of this jc
                s += __shfl_xor(s, 2);
                s += __shfl_xor(s, 4);
                s += __shfl_xor(s, 8);
                if (rowl == 0) atomicAdd(&ssrow[nf * 16 + g * 4 + r], s);
            }
        __syncthreads();
#pragma unroll
        for (int nf = 0; nf < 2; ++nf)
#pragma unroll
            for (int r = 0; r < 4; ++r) {
                int nrow = nf * 16 + g * 4 + r;
                int node = node0 + nrow;
                if (node < n) {
                    float sc = 1.0f / fmaxf(sqrtf(ssrow[nrow]), 1e-12f);
                    Outf[(size_t)node * 64 + j] = h[nf][r] * sc;
                }
            }
    }
}

// ---------------- launch ----------------

extern "C" void kernel_launch(void* const* d_in, const int* in_sizes, int n_in,
                              void* d_out, int out_size, void* d_ws, size_t ws_size,
                              hipStream_t stream) {
    const float* x = (const float*)d_in[0];
    const int* ei = (const int*)d_in[1];  // int32 staging
    const float* ew = (const float*)d_in[2];
    const float* W1l = (const float*)d_in[3];
    const float* b1 = (const float*)d_in[4];
    const float* W1r = (const float*)d_in[5];
    const float* W2l = (const float*)d_in[6];
    const float* b2 = (const float*)d_in[7];
    const float* W2r = (const float*)d_in[8];
    const float* W3l = (const float*)d_in[9];
    const float* b3 = (const float*)d_in[10];
    const float* W3r = (const float*)d_in[11];
    const float* bn1_g = (const float*)d_in[12];
    const float* bn1_b = (const float*)d_in[13];
    const float* bn1_m = (const float*)d_in[14];
    const float* bn1_v = (const float*)d_in[15];
    const float* bn2_g = (const float*)d_in[16];
    const float* bn2_b = (const float*)d_in[17];
    const float* bn2_m = (const float*)d_in[18];
    const float* bn2_v = (const float*)d_in[19];

    const int N = in_sizes[0] / IN_D;  // 50000
    const int E = in_sizes[2];         // 800000
    float* out = (float*)d_out;

    char* p = (char*)d_ws;
    auto alloc = [&](size_t bytes) -> void* {
        void* r = (void*)p;
        p += (bytes + 255) & ~(size_t)255;
        return r;
    };
    int* deg = (int*)alloc((size_t)N * 4);
    int* rowptr = (int*)alloc((size_t)(N + 1) * 4);
    int* cursor = (int*)alloc((size_t)N * 4);
    float* invcnt = (float*)alloc((size_t)N * 4);
    int* bsum = (int*)alloc(256 * 4);
    unsigned* csr = (unsigned*)alloc((size_t)(E + 16) * 4);  // 4B packed entries
    ushort* xb = (ushort*)alloc((size_t)N * 128 * 2);   // bf16 x
    ushort* Mb = (ushort*)alloc((size_t)N * 128 * 2);   // bf16 agg mean
    ushort* H1b = (ushort*)alloc((size_t)N * 128 * 2);  // bf16 layer outs
    ushort* H2b = (ushort*)alloc((size_t)N * 128 * 2);
    ushort* WB1 = (ushort*)alloc(32768 * 2);
    ushort* WB2 = (ushort*)alloc(32768 * 2);
    ushort* WB3 = (ushort*)alloc(16384 * 2);

    const int NB = (N + 255) / 256;
    const int EB = (E + 255) / 256;
    const int AGG_B = (N + 3) / 4;      // 4 waves (nodes) per 256-thread block
    const int GEMM_B = (N + 31) / 32;   // 32 nodes per block
    const int CVT_B = (N * 128 / 4 + 255) / 256;

    // --- CSR build + weight pack + x conversion ---
    hipMemsetAsync(deg, 0, (size_t)N * 4, stream);
    k_hist<<<EB, 256, 0, stream>>>(ei, deg, E, N);
    k_prep<<<320, 256, 0, stream>>>(W1l, W1r, W2l, W2r, W3l, W3r, WB1, WB2, WB3);
    k_cvt<<<CVT_B, 256, 0, stream>>>((const float4*)x, (ushort4*)xb, N * 128 / 4);
    k_block_sum<<<NB, 256, 0, stream>>>(deg, bsum, N);
    k_scan_bsum<<<1, 256, 0, stream>>>(bsum, NB);
    k_scan_deg<<<NB, 256, 0, stream>>>(deg, bsum, rowptr, cursor, invcnt, N);
    k_fill<<<EB, 256, 0, stream>>>(ei, ew, cursor, csr, E, N);

    // --- layer 1 ---
    k_agg<<<AGG_B, 256, 0, stream>>>((const uint2*)xb, rowptr, csr, invcnt,
                                     (uint2*)Mb, N);
    k_gemm5<128, 1><<<GEMM_B, 256, 0, stream>>>(Mb, xb, WB1, b1, bn1_g, bn1_b, bn1_m,
                                                bn1_v, (void*)H1b, N);
    // --- layer 2 ---
    k_agg<<<AGG_B, 256, 0, stream>>>((const uint2*)H1b, rowptr, csr, invcnt,
                                     (uint2*)Mb, N);
    k_gemm5<128, 1><<<GEMM_B, 256, 0, stream>>>(Mb, H1b, WB2, b2, bn2_g, bn2_b, bn2_m,
                                                bn2_v, (void*)H2b, N);
    // --- layer 3 (+ fused L2 normalize, f32 out) ---
    k_agg<<<AGG_B, 256, 0, stream>>>((const uint2*)H2b, rowptr, csr, invcnt,
                                     (uint2*)Mb, N);
    k_gemm5<64, 0><<<GEMM_B, 256, 0, stream>>>(Mb, H2b, WB3, b3, nullptr, nullptr,
                                               nullptr, nullptr, (void*)out, N);
}

// Round 13
// 364.729 us; speedup vs baseline: 1.0126x; 1.0126x over previous
//
#include <hip/hip_runtime.h>
#include <hip/hip_bf16.h>

#define IN_D 128
#define BN_EPS 1e-5f

typedef short bf8 __attribute__((ext_vector_type(8)));   // 8 bf16 = 4 VGPR (guide §3)
typedef float f32x4 __attribute__((ext_vector_type(4)));

__device__ __forceinline__ ushort f2bf(float f) {        // f32 -> bf16 RNE
    unsigned u = __float_as_uint(f);
    unsigned r = u + 0x7fffu + ((u >> 16) & 1u);
    return (ushort)(r >> 16);
}

// ---------------- CSR build ----------------
// edge_index staged int32. csr entry = 4B: {src:16 | bf16(weight):16}.

__global__ void k_hist(const int* __restrict__ ei, int* __restrict__ deg, int E, int n) {
    int e = blockIdx.x * 256 + threadIdx.x;
    if (e < E) {
        int dst = ei[E + e];
        if (dst >= 0 && dst < n) atomicAdd(&deg[dst], 1);
    }
}

__global__ void k_block_sum(const int* __restrict__ deg, int* __restrict__ bsum, int n) {
    __shared__ int sdata[256];
    int i = blockIdx.x * 256 + threadIdx.x;
    int v = (i < n) ? deg[i] : 0;
    sdata[threadIdx.x] = v;
    __syncthreads();
    for (int s = 128; s > 0; s >>= 1) {
        if (threadIdx.x < s) sdata[threadIdx.x] += sdata[threadIdx.x + s];
        __syncthreads();
    }
    if (threadIdx.x == 0) bsum[blockIdx.x] = sdata[0];
}

__global__ void k_scan_bsum(int* __restrict__ bsum, int nb) {
    __shared__ int s[256];
    int t = threadIdx.x;
    int v = (t < nb) ? bsum[t] : 0;
    s[t] = v;
    __syncthreads();
    for (int off = 1; off < 256; off <<= 1) {
        int u = (t >= off) ? s[t - off] : 0;
        __syncthreads();
        s[t] += u;
        __syncthreads();
    }
    if (t < nb) bsum[t] = s[t] - v;  // exclusive
}

__global__ void k_scan_deg(const int* __restrict__ deg, const int* __restrict__ boff,
                           int* __restrict__ rowptr, int* __restrict__ cursor,
                           float* __restrict__ invcnt, int n) {
    __shared__ int s[256];
    int t = threadIdx.x;
    int i = blockIdx.x * 256 + t;
    int v = (i < n) ? deg[i] : 0;
    s[t] = v;
    __syncthreads();
    for (int off = 1; off < 256; off <<= 1) {
        int u = (t >= off) ? s[t - off] : 0;
        __syncthreads();
        s[t] += u;
        __syncthreads();
    }
    int incl = s[t];
    int excl = incl - v;
    int base = boff[blockIdx.x];
    if (i < n) {
        rowptr[i] = base + excl;
        cursor[i] = base + excl;
        invcnt[i] = 1.0f / (float)(v < 1 ? 1 : v);
        if (i == n - 1) rowptr[n] = base + incl;
    }
}

// scatter store via atomicExch: atomics are performed in the L2 atomic units, so
// the line allocates/stays in L2 and 16 entries accumulate before one writeback
// (plain scatter stores took the no-allocate path: 64B HBM write per 4B entry, m12 data).
__global__ void k_fill(const int* __restrict__ ei, const float* __restrict__ ew,
                       int* __restrict__ cursor, unsigned* __restrict__ csr, int E,
                       int n) {
    int e = blockIdx.x * 256 + threadIdx.x;
    if (e < E) {
        int dst = ei[E + e];
        int src = ei[e];
        if (dst < 0 || dst >= n) return;
        if (src < 0) src = 0;
        if (src >= n) src = n - 1;
        int slot = atomicAdd(&cursor[dst], 1);
        atomicExch(&csr[slot],
                   (unsigned)(src & 0xffff) | ((unsigned)f2bf(ew[e]) << 16));
    }
}

// ---------------- x (f32) -> xb (bf16) ----------------
__global__ void k_cvt(const float4* __restrict__ X4, ushort4* __restrict__ Ob, int n4) {
    int i = blockIdx.x * 256 + threadIdx.x;
    if (i < n4) {
        float4 f = X4[i];
        ushort4 o;
        o.x = f2bf(f.x); o.y = f2bf(f.y); o.z = f2bf(f.z); o.w = f2bf(f.w);
        Ob[i] = o;
    }
}

// ---------------- W -> B-fragment-ordered bf16 pack (unchanged) ----------------
__global__ void k_prep(const float* __restrict__ W1l, const float* __restrict__ W1r,
                       const float* __restrict__ W2l, const float* __restrict__ W2r,
                       const float* __restrict__ W3l, const float* __restrict__ W3r,
                       ushort* __restrict__ WB1, ushort* __restrict__ WB2,
                       ushort* __restrict__ WB3) {
    int e = blockIdx.x * 256 + threadIdx.x;  // 0..81919
    const float *Wl, *Wr;
    ushort* dst;
    int idx;
    if (e < 32768)      { Wl = W1l; Wr = W1r; dst = WB1; idx = e; }
    else if (e < 65536) { Wl = W2l; Wr = W2r; dst = WB2; idx = e - 32768; }
    else                { Wl = W3l; Wr = W3r; dst = WB3; idx = e - 65536; }
    int ei = idx & 7, j0 = (idx >> 3) & 15, g = (idx >> 7) & 3, kc = (idx >> 9) & 7,
        jc = idx >> 12;
    int ksrc = (kc & 3) * 32 + g * 8 + ei;
    int jsrc = jc * 16 + j0;
    const float* src = (kc < 4) ? Wl : Wr;
    dst[idx] = f2bf(src[jsrc * 128 + ksrc]);
}

// ---------------- aggregation (round-11 structure, 4B entries) ----------------
// one wave per node; lane owns dims 2l,2l+1 (one uint = 2 bf16). 4x unroll;
// csr index is wave-uniform -> scalar loads; 4 row-gathers in flight.
__global__ void k_agg(const unsigned* __restrict__ Xb2, const int* __restrict__ rowptr,
                      const unsigned* __restrict__ csr, const float* __restrict__ invcnt,
                      unsigned* __restrict__ Mb2, int n) {
    int wid = (blockIdx.x * blockDim.x + threadIdx.x) >> 6;
    int lane = threadIdx.x & 63;
    if (wid >= n) return;
    int beg = __builtin_amdgcn_readfirstlane(rowptr[wid]);
    int end = __builtin_amdgcn_readfirstlane(rowptr[wid + 1]);
    float ax = 0.f, ay = 0.f;
    int k = beg;
    for (; k + 4 <= end; k += 4) {
        unsigned e0 = csr[k], e1 = csr[k + 1], e2 = csr[k + 2], e3 = csr[k + 3];
        unsigned v0 = Xb2[(size_t)(e0 & 0xffff) * 64 + lane];
        unsigned v1 = Xb2[(size_t)(e1 & 0xffff) * 64 + lane];
        unsigned v2 = Xb2[(size_t)(e2 & 0xffff) * 64 + lane];
        unsigned v3 = Xb2[(size_t)(e3 & 0xffff) * 64 + lane];
        float w0 = __uint_as_float(e0 & 0xffff0000u);
        float w1 = __uint_as_float(e1 & 0xffff0000u);
        float w2 = __uint_as_float(e2 & 0xffff0000u);
        float w3 = __uint_as_float(e3 & 0xffff0000u);
        ax += w0 * __uint_as_float(v0 << 16) + w1 * __uint_as_float(v1 << 16) +
              w2 * __uint_as_float(v2 << 16) + w3 * __uint_as_float(v3 << 16);
        ay += w0 * __uint_as_float(v0 & 0xffff0000u) +
              w1 * __uint_as_float(v1 & 0xffff0000u) +
              w2 * __uint_as_float(v2 & 0xffff0000u) +
              w3 * __uint_as_float(v3 & 0xffff0000u);
    }
    for (; k < end; ++k) {
        unsigned e = csr[k];
        float w = __uint_as_float(e & 0xffff0000u);
        unsigned v = Xb2[(size_t)(e & 0xffff) * 64 + lane];
        ax += w * __uint_as_float(v << 16);
        ay += w * __uint_as_float(v & 0xffff0000u);
    }
    float ic = invcnt[wid];
    Mb2[(size_t)wid * 64 + lane] =
        (unsigned)f2bf(ax * ic) | ((unsigned)f2bf(ay * ic) << 16);
}

// ---------------- GEMM v5: bf16 MFMA (unchanged) ----------------
template <int DO, int BN_FLAG>
__global__ __launch_bounds__(256) void k_gemm5(
    const ushort* __restrict__ Mb, const ushort* __restrict__ Xb,
    const ushort* __restrict__ WB, const float* __restrict__ bias,
    const float* __restrict__ bng, const float* __restrict__ bnb,
    const float* __restrict__ bnm, const float* __restrict__ bnv,
    void* __restrict__ OutP, int n) {
    constexpr int CF = DO / 64;
    __shared__ ushort sAb[32 * 256];  // 16 KB: [node][k] bf16, XOR-swizzled
    __shared__ float ssrow[32];

    int t = threadIdx.x;
    int wv = t >> 6;
    int lane = t & 63;
    int rowl = lane & 15;
    int g = lane >> 4;
    int node0 = blockIdx.x * 32;

    // ---- stage A = [M | X] tile (32 x 256 bf16), swizzle byte ^= (node&7)<<4 ----
    {
        const uint4* Ms = (const uint4*)(Mb + (size_t)node0 * 128);
        const uint4* Xs = (const uint4*)(Xb + (size_t)node0 * 128);
        uint4 z = make_uint4(0, 0, 0, 0);
#pragma unroll
        for (int it = 0; it < 4; ++it) {
            int idx = it * 256 + t;      // 1024 16B-units
            int nd = idx >> 5;           // node 0..31
            int u = idx & 31;            // 16B unit within 512B row
            bool ok = (node0 + nd) < n;
            uint4 vv = ok ? (u < 16 ? Ms[nd * 16 + u] : Xs[nd * 16 + (u - 16)]) : z;
            int byte = nd * 512 + ((u * 16) ^ ((nd & 7) << 4));
            *(uint4*)((char*)sAb + byte) = vv;
        }
        if (BN_FLAG == 0 && t < 32) ssrow[t] = 0.f;
    }
    __syncthreads();

    // ---- MFMA main loop: K = 256 = 8 kc-steps of 32 ----
    f32x4 acc[2][CF];
#pragma unroll
    for (int nf = 0; nf < 2; ++nf)
#pragma unroll
        for (int cf = 0; cf < CF; ++cf) acc[nf][cf] = (f32x4)0.f;

#pragma unroll
    for (int kc = 0; kc < 8; ++kc) {
        bf8 a[2];
#pragma unroll
        for (int nf = 0; nf < 2; ++nf) {
            int nl = nf * 16 + rowl;  // A-frag: row = lane&15, k = g*8+e
            int byte = nl * 512 + (((kc * 64) + g * 16) ^ ((nl & 7) << 4));
            a[nf] = *(const bf8*)((const char*)sAb + byte);
        }
#pragma unroll
        for (int cf = 0; cf < CF; ++cf) {
            int jc = wv * CF + cf;
            bf8 b = *(const bf8*)(WB + (((jc * 8 + kc) * 4 + g) * 128 + rowl * 8));
#pragma unroll
            for (int nf = 0; nf < 2; ++nf)
                acc[nf][cf] =
                    __builtin_amdgcn_mfma_f32_16x16x32_bf16(a[nf], b, acc[nf][cf], 0, 0, 0);
        }
    }

    // ---- epilogue ----
    if constexpr (BN_FLAG) {
        __syncthreads();               // done reading sAb; reuse as H tile
        ushort* sH = sAb;              // [32][DO] bf16
#pragma unroll
        for (int cf = 0; cf < CF; ++cf) {
            int j = (wv * CF + cf) * 16 + rowl;
            float bj = bias[j];
            float gm = bng[j], bb = bnb[j], mm = bnm[j];
            float iv = rsqrtf(bnv[j] + BN_EPS);
#pragma unroll
            for (int nf = 0; nf < 2; ++nf) {
#pragma unroll
                for (int r = 0; r < 4; ++r) {
                    int nrow = nf * 16 + g * 4 + r;  // C layout: row=(lane>>4)*4+r
                    float h = acc[nf][cf][r] + bj;
                    h = (h - mm) * (gm * iv) + bb;
                    h = h >= 0.f ? h : 0.1f * h;
                    sH[nrow * DO + j] = f2bf(h);
                }
            }
        }
        __syncthreads();
        ushort* Hout = (ushort*)OutP;
        constexpr int UPR = DO / 8;    // 16B-units per row
#pragma unroll
        for (int it = 0; it < (32 * UPR) / 256; ++it) {
            int u = it * 256 + t;
            int nd = u / UPR, c = u % UPR;
            if (node0 + nd < n)
                *(uint4*)(Hout + (size_t)(node0 + nd) * DO + c * 8) =
                    *(uint4*)&sH[nd * DO + c * 8];
        }
    } else {
        // DO==64, CF==1: bias + row L2-normalize, f32 out
        float* Outf = (float*)OutP;
        int j = wv * 16 + rowl;
        float bj = bias[j];
        float h[2][4];
#pragma unroll
        for (int nf = 0; nf < 2; ++nf)
#pragma unroll
            for (int r = 0; r < 4; ++r) {
                h[nf][r] = acc[nf][0][r] + bj;
                float s = h[nf][r] * h[nf][r];
                s += __shfl_xor(s, 1);   // reduce over 16 cols of this jc
                s += __shfl_xor(s, 2);
                s += __shfl_xor(s, 4);
                s += __shfl_xor(s, 8);
                if (rowl == 0) atomicAdd(&ssrow[nf * 16 + g * 4 + r], s);
            }
        __syncthreads();
#pragma unroll
        for (int nf = 0; nf < 2; ++nf)
#pragma unroll
            for (int r = 0; r < 4; ++r) {
                int nrow = nf * 16 + g * 4 + r;
                int node = node0 + nrow;
                if (node < n) {
                    float sc = 1.0f / fmaxf(sqrtf(ssrow[nrow]), 1e-12f);
                    Outf[(size_t)node * 64 + j] = h[nf][r] * sc;
                }
            }
    }
}

// ---------------- launch ----------------

extern "C" void kernel_launch(void* const* d_in, const int* in_sizes, int n_in,
                              void* d_out, int out_size, void* d_ws, size_t ws_size,
                              hipStream_t stream) {
    const float* x = (const float*)d_in[0];
    const int* ei = (const int*)d_in[1];  // int32 staging
    const float* ew = (const float*)d_in[2];
    const float* W1l = (const float*)d_in[3];
    const float* b1 = (const float*)d_in[4];
    const float* W1r = (const float*)d_in[5];
    const float* W2l = (const float*)d_in[6];
    const float* b2 = (const float*)d_in[7];
    const float* W2r = (const float*)d_in[8];
    const float* W3l = (const float*)d_in[9];
    const float* b3 = (const float*)d_in[10];
    const float* W3r = (const float*)d_in[11];
    const float* bn1_g = (const float*)d_in[12];
    const float* bn1_b = (const float*)d_in[13];
    const float* bn1_m = (const float*)d_in[14];
    const float* bn1_v = (const float*)d_in[15];
    const float* bn2_g = (const float*)d_in[16];
    const float* bn2_b = (const float*)d_in[17];
    const float* bn2_m = (const float*)d_in[18];
    const float* bn2_v = (const float*)d_in[19];

    const int N = in_sizes[0] / IN_D;  // 50000
    const int E = in_sizes[2];         // 800000
    float* out = (float*)d_out;

    char* p = (char*)d_ws;
    auto alloc = [&](size_t bytes) -> void* {
        void* r = (void*)p;
        p += (bytes + 255) & ~(size_t)255;
        return r;
    };
    int* deg = (int*)alloc((size_t)N * 4);
    int* rowptr = (int*)alloc((size_t)(N + 1) * 4);
    int* cursor = (int*)alloc((size_t)N * 4);
    float* invcnt = (float*)alloc((size_t)N * 4);
    int* bsum = (int*)alloc(256 * 4);
    unsigned* csr = (unsigned*)alloc((size_t)(E + 16) * 4);  // 4B packed entries
    ushort* xb = (ushort*)alloc((size_t)N * 128 * 2);   // bf16 x
    ushort* Mb = (ushort*)alloc((size_t)N * 128 * 2);   // bf16 agg mean
    ushort* H1b = (ushort*)alloc((size_t)N * 128 * 2);  // bf16 layer outs
    ushort* H2b = (ushort*)alloc((size_t)N * 128 * 2);
    ushort* WB1 = (ushort*)alloc(32768 * 2);
    ushort* WB2 = (ushort*)alloc(32768 * 2);
    ushort* WB3 = (ushort*)alloc(16384 * 2);

    const int NB = (N + 255) / 256;
    const int EB = (E + 255) / 256;
    const int AGG_B = (N + 3) / 4;      // 4 waves (nodes) per 256-thread block
    const int GEMM_B = (N + 31) / 32;   // 32 nodes per block
    const int CVT_B = (N * 128 / 4 + 255) / 256;

    // --- CSR build + weight pack + x conversion ---
    hipMemsetAsync(deg, 0, (size_t)N * 4, stream);
    k_hist<<<EB, 256, 0, stream>>>(ei, deg, E, N);
    k_prep<<<320, 256, 0, stream>>>(W1l, W1r, W2l, W2r, W3l, W3r, WB1, WB2, WB3);
    k_cvt<<<CVT_B, 256, 0, stream>>>((const float4*)x, (ushort4*)xb, N * 128 / 4);
    k_block_sum<<<NB, 256, 0, stream>>>(deg, bsum, N);
    k_scan_bsum<<<1, 256, 0, stream>>>(bsum, NB);
    k_scan_deg<<<NB, 256, 0, stream>>>(deg, bsum, rowptr, cursor, invcnt, N);
    k_fill<<<EB, 256, 0, stream>>>(ei, ew, cursor, csr, E, N);

    // --- layer 1 ---
    k_agg<<<AGG_B, 256, 0, stream>>>((const unsigned*)xb, rowptr, csr, invcnt,
                                     (unsigned*)Mb, N);
    k_gemm5<128, 1><<<GEMM_B, 256, 0, stream>>>(Mb, xb, WB1, b1, bn1_g, bn1_b, bn1_m,
                                                bn1_v, (void*)H1b, N);
    // --- layer 2 ---
    k_agg<<<AGG_B, 256, 0, stream>>>((const unsigned*)H1b, rowptr, csr, invcnt,
                                     (unsigned*)Mb, N);
    k_gemm5<128, 1><<<GEMM_B, 256, 0, stream>>>(Mb, H1b, WB2, b2, bn2_g, bn2_b, bn2_m,
                                                bn2_v, (void*)H2b, N);
    // --- layer 3 (+ fused L2 normalize, f32 out) ---
    k_agg<<<AGG_B, 256, 0, stream>>>((const unsigned*)H2b, rowptr, csr, invcnt,
                                     (unsigned*)Mb, N);
    k_gemm5<64, 0><<<GEMM_B, 256, 0, stream>>>(Mb, H2b, WB3, b3, nullptr, nullptr,
                                               nullptr, nullptr, (void*)out, N);
}